// Round 8
// baseline (890.625 us; speedup 1.0000x reference)
//
#include <hip/hip_runtime.h>
#include <cstdint>
#include <math.h>

constexpr int NN = 32768;
constexpr int KK = 4096;
constexpr int DD = 256;

typedef __attribute__((ext_vector_type(8))) short short8;
typedef __attribute__((ext_vector_type(4))) float f32x4;

// ---------- monotone float<->u32 (order-preserving incl. negatives) ----------
__device__ __forceinline__ unsigned mono(float v) {
  unsigned u = __float_as_uint(v);
  return (u & 0x80000000u) ? ~u : (u | 0x80000000u);
}
__device__ __forceinline__ float unmono(unsigned u) {
  u = (u & 0x80000000u) ? (u & 0x7fffffffu) : ~u;
  return __uint_as_float(u);
}

// ============ numpy-replica row sum-of-squares (verified bit-exact r2) ============
__device__ __forceinline__ void sq16(const float4* __restrict__ p, int b, float q[16]) {
#pragma unroll
  for (int j = 0; j < 4; ++j) {
    const float4 v = p[b * 4 + j];
    q[4 * j + 0] = v.x * v.x;
    q[4 * j + 1] = v.y * v.y;
    q[4 * j + 2] = v.z * v.z;
    q[4 * j + 3] = v.w * v.w;
  }
}
__device__ __forceinline__ float np_pw128_sq(const float4* __restrict__ p, int b0) {
  float A[16], B[16], r01[16], r23[16], q0123[16], r45[16], r67[16];
  sq16(p, b0 + 0, A); sq16(p, b0 + 1, B);
#pragma unroll
  for (int l = 0; l < 16; ++l) r01[l] = A[l] + B[l];
  sq16(p, b0 + 2, A); sq16(p, b0 + 3, B);
#pragma unroll
  for (int l = 0; l < 16; ++l) r23[l] = A[l] + B[l];
#pragma unroll
  for (int l = 0; l < 16; ++l) q0123[l] = r01[l] + r23[l];
  sq16(p, b0 + 4, A); sq16(p, b0 + 5, B);
#pragma unroll
  for (int l = 0; l < 16; ++l) r45[l] = A[l] + B[l];
  sq16(p, b0 + 6, A); sq16(p, b0 + 7, B);
#pragma unroll
  for (int l = 0; l < 16; ++l) r67[l] = A[l] + B[l];
  float s[16];
#pragma unroll
  for (int l = 0; l < 16; ++l) s[l] = q0123[l] + (r45[l] + r67[l]);
  float t[8];
#pragma unroll
  for (int l = 0; l < 8; ++l) t[l] = s[l] + s[l + 8];
  float u[4];
#pragma unroll
  for (int l = 0; l < 4; ++l) u[l] = t[l] + t[l + 4];
  return (u[0] + u[2]) + (u[1] + u[3]);
}

__global__ __launch_bounds__(256) void vq_norms(const float* __restrict__ src,
                                                float* __restrict__ dst, int nrows,
                                                unsigned long long* __restrict__ pmin) {
  const int row = blockIdx.x * blockDim.x + threadIdx.x;
  if (row >= nrows) return;
  const float4* p = reinterpret_cast<const float4*>(src + (size_t)row * DD);
  dst[row] = np_pw128_sq(p, 0) + np_pw128_sq(p, 8);
  if (pmin) pmin[row] = ~0ull;
}

__global__ __launch_bounds__(256) void vq_init(unsigned* __restrict__ tmin, int n) {
  const int i = blockIdx.x * blockDim.x + threadIdx.x;
  if (i < n) tmin[i] = 0xFFFFFFFFu;
}

// ---------- bf16 split helpers (identical numerics to round 7) ----------
__device__ __forceinline__ unsigned short bf16_rne(float f) {
  unsigned u = __float_as_uint(f);
  return (unsigned short)((u + 0x7fffu + ((u >> 16) & 1u)) >> 16);
}
__device__ __forceinline__ int swz16(int row, int k) {  // u16-element offset in [128][32] tile
  return (row * 32 + k) ^ ((row & 7) << 3);             // 16B-granule XOR swizzle
}

// ============ split kernel: fp32 -> (hi bf16, lo bf16) arrays ============
// One thread per 8 floats; grid sized exactly (counts divide evenly).
__global__ __launch_bounds__(256) void vq_split(const float* __restrict__ src,
                                                unsigned short* __restrict__ h,
                                                unsigned short* __restrict__ l) {
  const int i = blockIdx.x * blockDim.x + threadIdx.x;  // 8-float group index
  const float4 v0 = reinterpret_cast<const float4*>(src)[2 * i];
  const float4 v1 = reinterpret_cast<const float4*>(src)[2 * i + 1];
  const float f[8] = {v0.x, v0.y, v0.z, v0.w, v1.x, v1.y, v1.z, v1.w};
  unsigned hw[4], lw[4];
#pragma unroll
  for (int j = 0; j < 4; ++j) {
    const unsigned short h0 = bf16_rne(f[2 * j]), h1 = bf16_rne(f[2 * j + 1]);
    const float hf0 = __uint_as_float((unsigned)h0 << 16);
    const float hf1 = __uint_as_float((unsigned)h1 << 16);
    const unsigned short l0 = bf16_rne(f[2 * j] - hf0);
    const unsigned short l1 = bf16_rne(f[2 * j + 1] - hf1);
    hw[j] = (unsigned)h0 | ((unsigned)h1 << 16);
    lw[j] = (unsigned)l0 | ((unsigned)l1 << 16);
  }
  reinterpret_cast<uint4*>(h)[i] = make_uint4(hw[0], hw[1], hw[2], hw[3]);
  reinterpret_cast<uint4*>(l)[i] = make_uint4(lw[0], lw[1], lw[2], lw[3]);
}

// ============ MFMA approx pass, pre-split inputs, per-16k group mins ============
// P^ bit-identical to round 7 (same splits, same MFMA order, same epilogue fma).
// tmin16[row][g] (g = k/16) written by exactly ONE block -> plain stores.
__global__ __launch_bounds__(256) void vq_mfma_pre(const unsigned short* __restrict__ xh,
                                                   const unsigned short* __restrict__ xl,
                                                   const unsigned short* __restrict__ ch,
                                                   const unsigned short* __restrict__ cl,
                                                   const float* __restrict__ xn,
                                                   const float* __restrict__ cn,
                                                   unsigned* __restrict__ tmin16) {
  __shared__ __align__(16) unsigned short sXH[128 * 32];
  __shared__ __align__(16) unsigned short sXL[128 * 32];
  __shared__ __align__(16) unsigned short sCH[128 * 32];
  __shared__ __align__(16) unsigned short sCL[128 * 32];

  const int tid = threadIdx.x;
  const int lane = tid & 63;
  const int wid = tid >> 6;
  const int wm = wid >> 1, wn = wid & 1;
  const int row0 = blockIdx.x * 128;
  const int kc0 = blockIdx.y * 128;

  const int srow = tid >> 1;
  const int sh = (tid & 1) * 16;

  f32x4 acc[4][4];
#pragma unroll
  for (int m = 0; m < 4; ++m)
#pragma unroll
    for (int n = 0; n < 4; ++n) acc[m][n] = (f32x4)0.f;

  for (int dc = 0; dc < DD; dc += 32) {
    const size_t xoff = (size_t)(row0 + srow) * DD + dc + sh;
    const size_t coff = (size_t)(kc0 + srow) * DD + dc + sh;
    uint4 vxh[2], vxl[2], vch[2], vcl[2];
#pragma unroll
    for (int half = 0; half < 2; ++half) {
      vxh[half] = *reinterpret_cast<const uint4*>(xh + xoff + half * 8);
      vxl[half] = *reinterpret_cast<const uint4*>(xl + xoff + half * 8);
      vch[half] = *reinterpret_cast<const uint4*>(ch + coff + half * 8);
      vcl[half] = *reinterpret_cast<const uint4*>(cl + coff + half * 8);
    }
    __syncthreads();
#pragma unroll
    for (int half = 0; half < 2; ++half) {
      const int off = swz16(srow, sh + half * 8);
      *reinterpret_cast<uint4*>(&sXH[off]) = vxh[half];
      *reinterpret_cast<uint4*>(&sXL[off]) = vxl[half];
      *reinterpret_cast<uint4*>(&sCH[off]) = vch[half];
      *reinterpret_cast<uint4*>(&sCL[off]) = vcl[half];
    }
    __syncthreads();

    const int kg = (lane >> 4) * 8;
    short8 fbh[4], fbl[4];
#pragma unroll
    for (int n = 0; n < 4; ++n) {
      const int off = swz16(wn * 64 + n * 16 + (lane & 15), kg);
      fbh[n] = *reinterpret_cast<const short8*>(&sCH[off]);
      fbl[n] = *reinterpret_cast<const short8*>(&sCL[off]);
    }
#pragma unroll
    for (int m = 0; m < 4; ++m) {
      const int off = swz16(wm * 64 + m * 16 + (lane & 15), kg);
      const short8 fah = *reinterpret_cast<const short8*>(&sXH[off]);
      const short8 fal = *reinterpret_cast<const short8*>(&sXL[off]);
#pragma unroll
      for (int n = 0; n < 4; ++n) {
        acc[m][n] = __builtin_amdgcn_mfma_f32_16x16x32_bf16(fah, fbh[n], acc[m][n], 0, 0, 0);
        acc[m][n] = __builtin_amdgcn_mfma_f32_16x16x32_bf16(fah, fbl[n], acc[m][n], 0, 0, 0);
        acc[m][n] = __builtin_amdgcn_mfma_f32_16x16x32_bf16(fal, fbh[n], acc[m][n], 0, 0, 0);
      }
    }
  }

  // epilogue: per-(row, 16k-group) min; D layout col=lane&15, row=4*(lane>>4)+j
  const int lr = lane >> 4, lc = lane & 15;
  const int g0 = blockIdx.y * 8 + wn * 4;
#pragma unroll
  for (int m = 0; m < 4; ++m) {
    float xnv[4];
#pragma unroll
    for (int j = 0; j < 4; ++j) xnv[j] = xn[row0 + wm * 64 + m * 16 + lr * 4 + j];
    float p[4][4];  // [n][j]
#pragma unroll
    for (int n = 0; n < 4; ++n) {
      const float cnv = cn[kc0 + wn * 64 + n * 16 + lc];
#pragma unroll
      for (int j = 0; j < 4; ++j) {
        const float A = xnv[j] + cnv;
        p[n][j] = fmaf(-2.f, acc[m][n][j], A - xnv[j]);  // (A-xn) exact (Sterbenz)
      }
    }
#pragma unroll
    for (int off = 1; off < 16; off <<= 1) {
#pragma unroll
      for (int n = 0; n < 4; ++n)
#pragma unroll
        for (int j = 0; j < 4; ++j) p[n][j] = fminf(p[n][j], __shfl_xor(p[n][j], off));
    }
    if (lc == 0) {
#pragma unroll
      for (int n = 0; n < 4; ++n)
#pragma unroll
        for (int j = 0; j < 4; ++j) {
          const int row = row0 + wm * 64 + m * 16 + lr * 4 + j;
          tmin16[(size_t)row * 256 + g0 + n] = mono(p[n][j]);
        }
    }
  }
}

// ============ exact rescore, 16-k groups, LDS-staged coalesced ============
// Wave per row. Candidate groups (tmin16 <= gmin+W) are staged into LDS with
// coalesced float4 loads (full-line consumption), then each lane runs the
// exact ascending-d fp32 FMA chain for one k out of XOR-swizzled LDS.
__global__ __launch_bounds__(256) void vq_rescore16(const float* __restrict__ x,
                                                    const float* __restrict__ cb,
                                                    const float* __restrict__ xn,
                                                    const float* __restrict__ cn,
                                                    const unsigned* __restrict__ tmin16,
                                                    int* __restrict__ inds) {
  __shared__ __align__(16) float4 lds4[4 * (16 * 64 + 64)];  // 68 KB
  const int lane = threadIdx.x & 63;
  const int wv = threadIdx.x >> 6;
  const int row = blockIdx.x * 4 + wv;
  float4* cbuf = lds4 + wv * (16 * 64 + 64);
  float4* xbuf = cbuf + 16 * 64;

  // stage x row (1 KB, coalesced; broadcast reads later)
  xbuf[lane] = *reinterpret_cast<const float4*>(x + (size_t)row * DD + lane * 4);

  unsigned tv[4];
#pragma unroll
  for (int c = 0; c < 4; ++c) tv[c] = tmin16[(size_t)row * 256 + c * 64 + lane];
  unsigned mv = min(min(tv[0], tv[1]), min(tv[2], tv[3]));
#pragma unroll
  for (int off = 32; off; off >>= 1) mv = min(mv, (unsigned)__shfl_xor((int)mv, off));
  const float xnr = xn[row];
  const unsigned tq = mono(unmono(mv) + (xnr * 3e-7f + 4e-6f));  // same W as r7 (proven)

  unsigned long long best = ~0ull;
#pragma unroll 1
  for (int c = 0; c < 4; ++c) {
    unsigned long long qm = __ballot(tv[c] <= tq);
    while (qm) {
      const int s = __ffsll(qm) - 1;
      qm &= qm - 1;
      const int g = c * 64 + s;
      // stage 16 codebook rows (16 KB) coalesced, XOR-swizzled per row
#pragma unroll
      for (int it = 0; it < 4; ++it) {
        const int krow = it * 4 + (lane >> 4);
        const float4* src = reinterpret_cast<const float4*>(cb + (size_t)(g * 16 + krow) * DD);
#pragma unroll
        for (int q = 0; q < 4; ++q) {
          const int chk = (lane & 15) + q * 16;
          cbuf[krow * 64 + (chk ^ krow)] = src[chk];
        }
      }
      // exact ascending-d chain; lane handles k = g*16 + (lane&15)
      const int rr = lane & 15;
      float dot = 0.f;
#pragma unroll 8
      for (int cch = 0; cch < 64; ++cch) {
        const float4 cv = cbuf[rr * 64 + (cch ^ rr)];
        const float4 xv = xbuf[cch];
        dot = fmaf(xv.x, cv.x, dot);
        dot = fmaf(xv.y, cv.y, dot);
        dot = fmaf(xv.z, cv.z, dot);
        dot = fmaf(xv.w, cv.w, dot);
      }
      const int k = g * 16 + rr;
      const float A = xnr + cn[k];
      const float dist = fmaf(-2.f, dot, A);  // == fl(A - 2*dot), 2*dot exact
      const unsigned long long cand = ((unsigned long long)mono(dist) << 32) | (unsigned)k;
      best = best < cand ? best : cand;
    }
  }
#pragma unroll
  for (int off = 32; off; off >>= 1) {
    const unsigned long long o = __shfl_xor(best, off);
    best = best < o ? best : o;
  }
  if (lane == 0) inds[row] = (int)(best & 0xffffffffu);
}

// ================== round-7 fallback kernels (proven) ==================
__global__ __launch_bounds__(256) void vq_mfma(const float* __restrict__ x,
                                               const float* __restrict__ cb,
                                               const float* __restrict__ xn,
                                               const float* __restrict__ cn,
                                               unsigned* __restrict__ tmin) {
  __shared__ __align__(16) unsigned short sXH[128 * 32];
  __shared__ __align__(16) unsigned short sXL[128 * 32];
  __shared__ __align__(16) unsigned short sCH[128 * 32];
  __shared__ __align__(16) unsigned short sCL[128 * 32];

  const int tid = threadIdx.x;
  const int lane = tid & 63;
  const int wid = tid >> 6;
  const int wm = wid >> 1, wn = wid & 1;
  const int row0 = blockIdx.x * 128;
  const int kc0 = blockIdx.y * 128;
  const int srow = tid >> 1;
  const int sh = (tid & 1) * 16;

  f32x4 acc[4][4];
#pragma unroll
  for (int m = 0; m < 4; ++m)
#pragma unroll
    for (int n = 0; n < 4; ++n) acc[m][n] = (f32x4)0.f;

  for (int dc = 0; dc < DD; dc += 32) {
    const float4* xg = reinterpret_cast<const float4*>(x + (size_t)(row0 + srow) * DD + dc + sh);
    const float4* cg = reinterpret_cast<const float4*>(cb + (size_t)(kc0 + srow) * DD + dc + sh);
    float fx[16], fc[16];
#pragma unroll
    for (int j = 0; j < 4; ++j) {
      const float4 v = xg[j];
      fx[4 * j] = v.x; fx[4 * j + 1] = v.y; fx[4 * j + 2] = v.z; fx[4 * j + 3] = v.w;
    }
#pragma unroll
    for (int j = 0; j < 4; ++j) {
      const float4 v = cg[j];
      fc[4 * j] = v.x; fc[4 * j + 1] = v.y; fc[4 * j + 2] = v.z; fc[4 * j + 3] = v.w;
    }
    unsigned xhw[8], xlw[8], chw[8], clw[8];
#pragma unroll
    for (int j = 0; j < 8; ++j) {
      unsigned short h0 = bf16_rne(fx[2 * j]), h1 = bf16_rne(fx[2 * j + 1]);
      float hf0 = __uint_as_float((unsigned)h0 << 16), hf1 = __uint_as_float((unsigned)h1 << 16);
      unsigned short l0 = bf16_rne(fx[2 * j] - hf0), l1 = bf16_rne(fx[2 * j + 1] - hf1);
      xhw[j] = (unsigned)h0 | ((unsigned)h1 << 16);
      xlw[j] = (unsigned)l0 | ((unsigned)l1 << 16);
      h0 = bf16_rne(fc[2 * j]); h1 = bf16_rne(fc[2 * j + 1]);
      hf0 = __uint_as_float((unsigned)h0 << 16); hf1 = __uint_as_float((unsigned)h1 << 16);
      l0 = bf16_rne(fc[2 * j] - hf0); l1 = bf16_rne(fc[2 * j + 1] - hf1);
      chw[j] = (unsigned)h0 | ((unsigned)h1 << 16);
      clw[j] = (unsigned)l0 | ((unsigned)l1 << 16);
    }
    __syncthreads();
#pragma unroll
    for (int half = 0; half < 2; ++half) {
      const int off = swz16(srow, sh + half * 8);
      *reinterpret_cast<uint4*>(&sXH[off]) = make_uint4(xhw[4 * half], xhw[4 * half + 1], xhw[4 * half + 2], xhw[4 * half + 3]);
      *reinterpret_cast<uint4*>(&sXL[off]) = make_uint4(xlw[4 * half], xlw[4 * half + 1], xlw[4 * half + 2], xlw[4 * half + 3]);
      *reinterpret_cast<uint4*>(&sCH[off]) = make_uint4(chw[4 * half], chw[4 * half + 1], chw[4 * half + 2], chw[4 * half + 3]);
      *reinterpret_cast<uint4*>(&sCL[off]) = make_uint4(clw[4 * half], clw[4 * half + 1], clw[4 * half + 2], clw[4 * half + 3]);
    }
    __syncthreads();

    const int kg = (lane >> 4) * 8;
    short8 fbh[4], fbl[4];
#pragma unroll
    for (int n = 0; n < 4; ++n) {
      const int off = swz16(wn * 64 + n * 16 + (lane & 15), kg);
      fbh[n] = *reinterpret_cast<const short8*>(&sCH[off]);
      fbl[n] = *reinterpret_cast<const short8*>(&sCL[off]);
    }
#pragma unroll
    for (int m = 0; m < 4; ++m) {
      const int off = swz16(wm * 64 + m * 16 + (lane & 15), kg);
      const short8 fah = *reinterpret_cast<const short8*>(&sXH[off]);
      const short8 fal = *reinterpret_cast<const short8*>(&sXL[off]);
#pragma unroll
      for (int n = 0; n < 4; ++n) {
        acc[m][n] = __builtin_amdgcn_mfma_f32_16x16x32_bf16(fah, fbh[n], acc[m][n], 0, 0, 0);
        acc[m][n] = __builtin_amdgcn_mfma_f32_16x16x32_bf16(fah, fbl[n], acc[m][n], 0, 0, 0);
        acc[m][n] = __builtin_amdgcn_mfma_f32_16x16x32_bf16(fal, fbh[n], acc[m][n], 0, 0, 0);
      }
    }
  }

  const int lr = lane >> 4, lc = lane & 15;
  const int tile = blockIdx.y * 2 + wn;
#pragma unroll
  for (int m = 0; m < 4; ++m) {
    float xnv[4];
#pragma unroll
    for (int j = 0; j < 4; ++j) xnv[j] = xn[row0 + wm * 64 + m * 16 + lr * 4 + j];
    float pm[4] = {INFINITY, INFINITY, INFINITY, INFINITY};
#pragma unroll
    for (int n = 0; n < 4; ++n) {
      const float cnv = cn[kc0 + wn * 64 + n * 16 + lc];
#pragma unroll
      for (int j = 0; j < 4; ++j) {
        const float A = xnv[j] + cnv;
        const float p = fmaf(-2.f, acc[m][n][j], A - xnv[j]);
        pm[j] = fminf(pm[j], p);
      }
    }
#pragma unroll
    for (int off = 1; off < 16; off <<= 1) {
#pragma unroll
      for (int j = 0; j < 4; ++j) pm[j] = fminf(pm[j], __shfl_xor(pm[j], off));
    }
    if (lc == 0) {
#pragma unroll
      for (int j = 0; j < 4; ++j) {
        const int row = row0 + wm * 64 + m * 16 + lr * 4 + j;
        atomicMin(&tmin[(size_t)row * 64 + tile], mono(pm[j]));
      }
    }
  }
}

__global__ __launch_bounds__(256) void vq_rescore(const float* __restrict__ x,
                                                  const float* __restrict__ cb,
                                                  const float* __restrict__ xn,
                                                  const float* __restrict__ cn,
                                                  const unsigned* __restrict__ tmin,
                                                  int* __restrict__ inds) {
  const int lane = threadIdx.x & 63;
  const int row = blockIdx.x * 4 + (threadIdx.x >> 6);
  const unsigned tv = tmin[(size_t)row * 64 + lane];
  unsigned mv = tv;
#pragma unroll
  for (int off = 32; off; off >>= 1) mv = min(mv, (unsigned)__shfl_xor((int)mv, off));
  const float xnr = xn[row];
  const float thresh = unmono(mv) + (xnr * 3e-7f + 4e-6f);
  const unsigned tq = mono(thresh);
  unsigned long long qmask = __ballot(tv <= tq);

  const float* xp = x + (size_t)row * DD;
  unsigned long long best = ~0ull;
  while (qmask) {
    const int s = __ffsll(qmask) - 1;
    qmask &= qmask - 1;
    const int k = s * 64 + lane;
    const float* cp = cb + (size_t)k * DD;
    float dot = 0.f;
#pragma unroll 8
    for (int d = 0; d < DD; ++d) dot = fmaf(xp[d], cp[d], dot);
    const float A = xnr + cn[k];
    const float dist = fmaf(-2.f, dot, A);
    const unsigned long long cand = ((unsigned long long)mono(dist) << 32) | (unsigned)k;
    best = best < cand ? best : cand;
  }
#pragma unroll
  for (int off = 32; off; off >>= 1) {
    const unsigned long long o = __shfl_xor(best, off);
    best = best < o ? best : o;
  }
  if (lane == 0) inds[row] = (int)(best & 0xffffffffu);
}

// ============ gather + STE output ============
__global__ __launch_bounds__(256) void vq_out(const float* __restrict__ x,
                                              const float* __restrict__ cb,
                                              const int* __restrict__ inds,
                                              float* __restrict__ out) {
  const int w = (blockIdx.x * blockDim.x + threadIdx.x) >> 6;
  const int lane = threadIdx.x & 63;
  if (w >= NN) return;
  const int k = inds[w];
  const float4 xv = *reinterpret_cast<const float4*>(x + (size_t)w * DD + lane * 4);
  const float4 cv = *reinterpret_cast<const float4*>(cb + (size_t)k * DD + lane * 4);
  float4 o;
  o.x = xv.x + (cv.x - xv.x);
  o.y = xv.y + (cv.y - xv.y);
  o.z = xv.z + (cv.z - xv.z);
  o.w = xv.w + (cv.w - xv.w);
  *reinterpret_cast<float4*>(out + (size_t)w * DD + lane * 4) = o;
}

extern "C" void kernel_launch(void* const* d_in, const int* in_sizes, int n_in,
                              void* d_out, int out_size, void* d_ws, size_t ws_size,
                              hipStream_t stream) {
  const float* x = (const float*)d_in[0];
  const float* cb = (const float*)d_in[1];
  float* out = (float*)d_out;
  char* ws = (char*)d_ws;

  // common: xn @0 (128KB), cn @128K (16KB)
  float* xn = (float*)ws;
  float* cn = (float*)(ws + 131072);
  constexpr size_t BASE = 147456;

  // fast-path layout
  constexpr size_t XH_OFF = BASE;
  constexpr size_t XL_OFF = XH_OFF + (size_t)NN * DD * 2;       // +16MB
  constexpr size_t CH_OFF = XL_OFF + (size_t)NN * DD * 2;       // +16MB
  constexpr size_t CL_OFF = CH_OFF + (size_t)KK * DD * 2;       // +2MB
  constexpr size_t T16_OFF = CL_OFF + (size_t)KK * DD * 2;      // +2MB
  constexpr size_t INDS_OFF = T16_OFF + (size_t)NN * 256 * 4;   // +32MB
  constexpr size_t NEED_FAST = INDS_OFF + (size_t)NN * 4;       // ~68.3MB

  if (ws_size >= NEED_FAST) {
    unsigned short* xh = (unsigned short*)(ws + XH_OFF);
    unsigned short* xl = (unsigned short*)(ws + XL_OFF);
    unsigned short* ch = (unsigned short*)(ws + CH_OFF);
    unsigned short* cl = (unsigned short*)(ws + CL_OFF);
    unsigned* tmin16 = (unsigned*)(ws + T16_OFF);
    int* inds = (int*)(ws + INDS_OFF);

    vq_norms<<<NN / 256, 256, 0, stream>>>(x, xn, NN, nullptr);
    vq_norms<<<KK / 256, 256, 0, stream>>>(cb, cn, KK, nullptr);
    vq_split<<<(NN * DD / 8) / 256, 256, 0, stream>>>(x, xh, xl);
    vq_split<<<(KK * DD / 8) / 256, 256, 0, stream>>>(cb, ch, cl);
    dim3 mgrid(NN / 128, KK / 128);
    vq_mfma_pre<<<mgrid, 256, 0, stream>>>(xh, xl, ch, cl, xn, cn, tmin16);
    vq_rescore16<<<NN / 4, 256, 0, stream>>>(x, cb, xn, cn, tmin16, inds);
    vq_out<<<NN / 4, 256, 0, stream>>>(x, cb, inds, out);
  } else {
    // round-7 fallback (proven): tmin64 @BASE (8MB), inds after
    unsigned* tmin = (unsigned*)(ws + BASE);
    int* inds = (int*)(ws + BASE + (size_t)NN * 64 * 4);
    unsigned long long* pmin_unused = nullptr;
    (void)pmin_unused;

    vq_init<<<(NN * 64) / 256, 256, 0, stream>>>(tmin, NN * 64);
    vq_norms<<<NN / 256, 256, 0, stream>>>(x, xn, NN, nullptr);
    vq_norms<<<KK / 256, 256, 0, stream>>>(cb, cn, KK, nullptr);
    dim3 mgrid(NN / 128, KK / 128);
    vq_mfma<<<mgrid, 256, 0, stream>>>(x, cb, xn, cn, tmin);
    vq_rescore<<<NN / 4, 256, 0, stream>>>(x, cb, xn, cn, tmin, inds);
    vq_out<<<NN / 4, 256, 0, stream>>>(x, cb, inds, out);
  }
}

// Round 9
// 317.871 us; speedup vs baseline: 2.8018x; 2.8018x over previous
//
#include <hip/hip_runtime.h>
#include <cstdint>
#include <math.h>

constexpr int NN = 32768;
constexpr int KK = 4096;
constexpr int DD = 256;

typedef __attribute__((ext_vector_type(8))) short short8;
typedef __attribute__((ext_vector_type(4))) float f32x4;

#define AS1 __attribute__((address_space(1)))
#define AS3 __attribute__((address_space(3)))

// async 16B global->LDS: per-lane global src, wave-uniform LDS base (+lane*16 by HW)
__device__ __forceinline__ void gload16(unsigned short* lds_dst, const unsigned short* gsrc) {
  __builtin_amdgcn_global_load_lds((const AS1 unsigned int*)gsrc, (AS3 unsigned int*)lds_dst,
                                   16, 0, 0);
}

// ---------- monotone float<->u32 (order-preserving incl. negatives) ----------
__device__ __forceinline__ unsigned mono(float v) {
  unsigned u = __float_as_uint(v);
  return (u & 0x80000000u) ? ~u : (u | 0x80000000u);
}
__device__ __forceinline__ float unmono(unsigned u) {
  u = (u & 0x80000000u) ? (u & 0x7fffffffu) : ~u;
  return __uint_as_float(u);
}

// ============ numpy-replica row sum-of-squares (verified bit-exact r2) ============
__device__ __forceinline__ void sq16(const float4* __restrict__ p, int b, float q[16]) {
#pragma unroll
  for (int j = 0; j < 4; ++j) {
    const float4 v = p[b * 4 + j];
    q[4 * j + 0] = v.x * v.x;
    q[4 * j + 1] = v.y * v.y;
    q[4 * j + 2] = v.z * v.z;
    q[4 * j + 3] = v.w * v.w;
  }
}
__device__ __forceinline__ float np_pw128_sq(const float4* __restrict__ p, int b0) {
  float A[16], B[16], r01[16], r23[16], q0123[16], r45[16], r67[16];
  sq16(p, b0 + 0, A); sq16(p, b0 + 1, B);
#pragma unroll
  for (int l = 0; l < 16; ++l) r01[l] = A[l] + B[l];
  sq16(p, b0 + 2, A); sq16(p, b0 + 3, B);
#pragma unroll
  for (int l = 0; l < 16; ++l) r23[l] = A[l] + B[l];
#pragma unroll
  for (int l = 0; l < 16; ++l) q0123[l] = r01[l] + r23[l];
  sq16(p, b0 + 4, A); sq16(p, b0 + 5, B);
#pragma unroll
  for (int l = 0; l < 16; ++l) r45[l] = A[l] + B[l];
  sq16(p, b0 + 6, A); sq16(p, b0 + 7, B);
#pragma unroll
  for (int l = 0; l < 16; ++l) r67[l] = A[l] + B[l];
  float s[16];
#pragma unroll
  for (int l = 0; l < 16; ++l) s[l] = q0123[l] + (r45[l] + r67[l]);
  float t[8];
#pragma unroll
  for (int l = 0; l < 8; ++l) t[l] = s[l] + s[l + 8];
  float u[4];
#pragma unroll
  for (int l = 0; l < 4; ++l) u[l] = t[l] + t[l + 4];
  return (u[0] + u[2]) + (u[1] + u[3]);
}

__global__ __launch_bounds__(256) void vq_norms(const float* __restrict__ src,
                                                float* __restrict__ dst, int nrows) {
  const int row = blockIdx.x * blockDim.x + threadIdx.x;
  if (row >= nrows) return;
  const float4* p = reinterpret_cast<const float4*>(src + (size_t)row * DD);
  dst[row] = np_pw128_sq(p, 0) + np_pw128_sq(p, 8);
}

__global__ __launch_bounds__(256) void vq_init(unsigned* __restrict__ tmin, int n) {
  const int i = blockIdx.x * blockDim.x + threadIdx.x;
  if (i < n) tmin[i] = 0xFFFFFFFFu;
}

// ---------- bf16 helpers ----------
__device__ __forceinline__ unsigned short bf16_rne(float f) {
  unsigned u = __float_as_uint(f);
  return (unsigned short)((u + 0x7fffu + ((u >> 16) & 1u)) >> 16);
}
__device__ __forceinline__ int swz16(int row, int k) {  // r7/fallback swizzle
  return (row * 32 + k) ^ ((row & 7) << 3);
}

// ============ split kernel: fp32 -> hi bf16, PRE-SWIZZLED tile image ============
// Tile image: per (rowblk, dcblk) an 8KB block of [128 rows][4 chunks of 16B],
// with chunk' = chunk ^ ((row>>1)&3).  A linear 16B-per-lane copy of this block
// into LDS reproduces the swizzled image the fragment reads expect.
__global__ __launch_bounds__(256) void vq_split_hi(const float* __restrict__ src,
                                                   unsigned short* __restrict__ hi) {
  const int i = blockIdx.x * blockDim.x + threadIdx.x;  // 8-float group index
  const float4 v0 = reinterpret_cast<const float4*>(src)[2 * i];
  const float4 v1 = reinterpret_cast<const float4*>(src)[2 * i + 1];
  const float f[8] = {v0.x, v0.y, v0.z, v0.w, v1.x, v1.y, v1.z, v1.w};
  unsigned hw[4];
#pragma unroll
  for (int j = 0; j < 4; ++j)
    hw[j] = (unsigned)bf16_rne(f[2 * j]) | ((unsigned)bf16_rne(f[2 * j + 1]) << 16);
  const int e0 = i * 8;
  const int row = e0 >> 8, d0 = e0 & 255;
  const int dcb = d0 >> 5, k = d0 & 31, chunk = k >> 3;
  const int r = row & 127, rb = row >> 7;
  const int cs = chunk ^ ((r >> 1) & 3);
  reinterpret_cast<uint4*>(hi)[(size_t)(rb * 8 + dcb) * 512 + r * 4 + cs] =
      make_uint4(hw[0], hw[1], hw[2], hw[3]);
}

// ============ 1-term bf16 MFMA approx pass ============
// mm^ = xh*ch (fp32 MFMA accum). P^ = (fl(xn+cn)-xn) - 2*mm^.
// |P^ - (dist-xn)| <= ulp(dist) + 2|mm err|, covered by rescore window W.
// tmin16[row][g] (g=k/16) written by exactly one block -> plain stores.
__global__ __launch_bounds__(256) void vq_mfma2(const unsigned short* __restrict__ xh,
                                                const unsigned short* __restrict__ ch,
                                                const float* __restrict__ xn,
                                                const float* __restrict__ cn,
                                                unsigned* __restrict__ tmin16) {
  __shared__ __align__(16) unsigned short sX[4096];  // 8KB swizzled tile image
  __shared__ __align__(16) unsigned short sC[4096];

  const int tid = threadIdx.x;
  const int lane = tid & 63;
  const int w = tid >> 6;
  const int wm = w >> 1, wn = w & 1;
  const int bx = blockIdx.x;  // col-block 0..31
  const int by = blockIdx.y;  // row-block 0..255
  const int row0 = by * 128, kc0 = bx * 128;

  f32x4 acc[4][4];
#pragma unroll
  for (int m = 0; m < 4; ++m)
#pragma unroll
    for (int n = 0; n < 4; ++n) acc[m][n] = (f32x4)0.f;

  const int r = lane & 15, g = lane >> 4;
  const int fo = (g ^ ((r >> 1) & 3)) * 8;  // swizzled chunk offset (u16)

  for (int dc8 = 0; dc8 < 8; ++dc8) {
    const unsigned short* xt = xh + (size_t)(by * 8 + dc8) * 4096;
    const unsigned short* ct = ch + (size_t)(bx * 8 + dc8) * 4096;
    __syncthreads();  // prior iteration's fragment reads done
    // wave w copies 1KB segments {2w,2w+1} of each tile, linearly
#pragma unroll
    for (int j = 0; j < 2; ++j) {
      const int seg = 2 * w + j;
      gload16(sX + seg * 512, xt + seg * 512 + lane * 8);
      gload16(sC + seg * 512, ct + seg * 512 + lane * 8);
    }
    asm volatile("s_waitcnt vmcnt(0)" ::: "memory");
    __syncthreads();

    short8 fb[4];
#pragma unroll
    for (int n = 0; n < 4; ++n)
      fb[n] = *reinterpret_cast<const short8*>(&sC[(wn * 64 + n * 16 + r) * 32 + fo]);
#pragma unroll
    for (int m = 0; m < 4; ++m) {
      const short8 fa = *reinterpret_cast<const short8*>(&sX[(wm * 64 + m * 16 + r) * 32 + fo]);
#pragma unroll
      for (int n = 0; n < 4; ++n)
        acc[m][n] = __builtin_amdgcn_mfma_f32_16x16x32_bf16(fa, fb[n], acc[m][n], 0, 0, 0);
    }
  }

  // epilogue (r8-verified): per-(row,16k-group) min; D layout col=lane&15, row=4*(lane>>4)+j
  const int lr = lane >> 4, lc = lane & 15;
  const int g0 = bx * 8 + wn * 4;
#pragma unroll
  for (int m = 0; m < 4; ++m) {
    float xnv[4];
#pragma unroll
    for (int j = 0; j < 4; ++j) xnv[j] = xn[row0 + wm * 64 + m * 16 + lr * 4 + j];
    float p[4][4];  // [n][j]
#pragma unroll
    for (int n = 0; n < 4; ++n) {
      const float cnv = cn[kc0 + wn * 64 + n * 16 + lc];
#pragma unroll
      for (int j = 0; j < 4; ++j) {
        const float A = xnv[j] + cnv;
        p[n][j] = fmaf(-2.f, acc[m][n][j], A - xnv[j]);  // (A-xn) exact (Sterbenz)
      }
    }
#pragma unroll
    for (int off = 1; off < 16; off <<= 1) {
#pragma unroll
      for (int n = 0; n < 4; ++n)
#pragma unroll
        for (int j = 0; j < 4; ++j) p[n][j] = fminf(p[n][j], __shfl_xor(p[n][j], off));
    }
    if (lc == 0) {
#pragma unroll
      for (int n = 0; n < 4; ++n)
#pragma unroll
        for (int j = 0; j < 4; ++j) {
          const int row = row0 + wm * 64 + m * 16 + lr * 4 + j;
          tmin16[(size_t)row * 256 + g0 + n] = mono(p[n][j]);
        }
    }
  }
}

// ============ exact rescore, 16-k groups, LDS-staged coalesced (r8-verified) ============
__global__ __launch_bounds__(256) void vq_rescore16(const float* __restrict__ x,
                                                    const float* __restrict__ cb,
                                                    const float* __restrict__ xn,
                                                    const float* __restrict__ cn,
                                                    const unsigned* __restrict__ tmin16,
                                                    int* __restrict__ inds) {
  __shared__ __align__(16) float4 lds4[4 * (16 * 64 + 64)];  // 68 KB
  const int lane = threadIdx.x & 63;
  const int wv = threadIdx.x >> 6;
  const int row = blockIdx.x * 4 + wv;
  float4* cbuf = lds4 + wv * (16 * 64 + 64);
  float4* xbuf = cbuf + 16 * 64;

  xbuf[lane] = *reinterpret_cast<const float4*>(x + (size_t)row * DD + lane * 4);

  unsigned tv[4];
#pragma unroll
  for (int c = 0; c < 4; ++c) tv[c] = tmin16[(size_t)row * 256 + c * 64 + lane];
  unsigned mv = min(min(tv[0], tv[1]), min(tv[2], tv[3]));
#pragma unroll
  for (int off = 32; off; off >>= 1) mv = min(mv, (unsigned)__shfl_xor((int)mv, off));
  const float xnr = xn[row];
  // W = ulp-cover + 1-term bf16 GEMM error margin (2e-4 ~ 45 sigma of dot-err)
  const unsigned tq = mono(unmono(mv) + (xnr * 3e-7f + 2e-4f));

  unsigned long long best = ~0ull;
#pragma unroll 1
  for (int c = 0; c < 4; ++c) {
    unsigned long long qm = __ballot(tv[c] <= tq);
    while (qm) {
      const int s = __ffsll(qm) - 1;
      qm &= qm - 1;
      const int g = c * 64 + s;
#pragma unroll
      for (int it = 0; it < 4; ++it) {
        const int krow = it * 4 + (lane >> 4);
        const float4* src = reinterpret_cast<const float4*>(cb + (size_t)(g * 16 + krow) * DD);
#pragma unroll
        for (int q = 0; q < 4; ++q) {
          const int chk = (lane & 15) + q * 16;
          cbuf[krow * 64 + (chk ^ krow)] = src[chk];
        }
      }
      const int rr = lane & 15;
      float dot = 0.f;
#pragma unroll 8
      for (int cch = 0; cch < 64; ++cch) {
        const float4 cv = cbuf[rr * 64 + (cch ^ rr)];
        const float4 xv = xbuf[cch];
        dot = fmaf(xv.x, cv.x, dot);
        dot = fmaf(xv.y, cv.y, dot);
        dot = fmaf(xv.z, cv.z, dot);
        dot = fmaf(xv.w, cv.w, dot);
      }
      const int k = g * 16 + rr;
      const float A = xnr + cn[k];
      const float dist = fmaf(-2.f, dot, A);  // == fl(A - 2*dot), 2*dot exact
      const unsigned long long cand = ((unsigned long long)mono(dist) << 32) | (unsigned)k;
      best = best < cand ? best : cand;
    }
  }
#pragma unroll
  for (int off = 32; off; off >>= 1) {
    const unsigned long long o = __shfl_xor(best, off);
    best = best < o ? best : o;
  }
  if (lane == 0) inds[row] = (int)(best & 0xffffffffu);
}

// ================== round-7 fallback kernels (proven) ==================
__global__ __launch_bounds__(256) void vq_mfma(const float* __restrict__ x,
                                               const float* __restrict__ cb,
                                               const float* __restrict__ xn,
                                               const float* __restrict__ cn,
                                               unsigned* __restrict__ tmin) {
  __shared__ __align__(16) unsigned short sXH[128 * 32];
  __shared__ __align__(16) unsigned short sXL[128 * 32];
  __shared__ __align__(16) unsigned short sCH[128 * 32];
  __shared__ __align__(16) unsigned short sCL[128 * 32];

  const int tid = threadIdx.x;
  const int lane = tid & 63;
  const int wid = tid >> 6;
  const int wm = wid >> 1, wn = wid & 1;
  const int row0 = blockIdx.x * 128;
  const int kc0 = blockIdx.y * 128;
  const int srow = tid >> 1;
  const int sh = (tid & 1) * 16;

  f32x4 acc[4][4];
#pragma unroll
  for (int m = 0; m < 4; ++m)
#pragma unroll
    for (int n = 0; n < 4; ++n) acc[m][n] = (f32x4)0.f;

  for (int dc = 0; dc < DD; dc += 32) {
    const float4* xg = reinterpret_cast<const float4*>(x + (size_t)(row0 + srow) * DD + dc + sh);
    const float4* cg = reinterpret_cast<const float4*>(cb + (size_t)(kc0 + srow) * DD + dc + sh);
    float fx[16], fc[16];
#pragma unroll
    for (int j = 0; j < 4; ++j) {
      const float4 v = xg[j];
      fx[4 * j] = v.x; fx[4 * j + 1] = v.y; fx[4 * j + 2] = v.z; fx[4 * j + 3] = v.w;
    }
#pragma unroll
    for (int j = 0; j < 4; ++j) {
      const float4 v = cg[j];
      fc[4 * j] = v.x; fc[4 * j + 1] = v.y; fc[4 * j + 2] = v.z; fc[4 * j + 3] = v.w;
    }
    unsigned xhw[8], xlw[8], chw[8], clw[8];
#pragma unroll
    for (int j = 0; j < 8; ++j) {
      unsigned short h0 = bf16_rne(fx[2 * j]), h1 = bf16_rne(fx[2 * j + 1]);
      float hf0 = __uint_as_float((unsigned)h0 << 16), hf1 = __uint_as_float((unsigned)h1 << 16);
      unsigned short l0 = bf16_rne(fx[2 * j] - hf0), l1 = bf16_rne(fx[2 * j + 1] - hf1);
      xhw[j] = (unsigned)h0 | ((unsigned)h1 << 16);
      xlw[j] = (unsigned)l0 | ((unsigned)l1 << 16);
      h0 = bf16_rne(fc[2 * j]); h1 = bf16_rne(fc[2 * j + 1]);
      hf0 = __uint_as_float((unsigned)h0 << 16); hf1 = __uint_as_float((unsigned)h1 << 16);
      l0 = bf16_rne(fc[2 * j] - hf0); l1 = bf16_rne(fc[2 * j + 1] - hf1);
      chw[j] = (unsigned)h0 | ((unsigned)h1 << 16);
      clw[j] = (unsigned)l0 | ((unsigned)l1 << 16);
    }
    __syncthreads();
#pragma unroll
    for (int half = 0; half < 2; ++half) {
      const int off = swz16(srow, sh + half * 8);
      *reinterpret_cast<uint4*>(&sXH[off]) = make_uint4(xhw[4 * half], xhw[4 * half + 1], xhw[4 * half + 2], xhw[4 * half + 3]);
      *reinterpret_cast<uint4*>(&sXL[off]) = make_uint4(xlw[4 * half], xlw[4 * half + 1], xlw[4 * half + 2], xlw[4 * half + 3]);
      *reinterpret_cast<uint4*>(&sCH[off]) = make_uint4(chw[4 * half], chw[4 * half + 1], chw[4 * half + 2], chw[4 * half + 3]);
      *reinterpret_cast<uint4*>(&sCL[off]) = make_uint4(clw[4 * half], clw[4 * half + 1], clw[4 * half + 2], clw[4 * half + 3]);
    }
    __syncthreads();

    const int kg = (lane >> 4) * 8;
    short8 fbh[4], fbl[4];
#pragma unroll
    for (int n = 0; n < 4; ++n) {
      const int off = swz16(wn * 64 + n * 16 + (lane & 15), kg);
      fbh[n] = *reinterpret_cast<const short8*>(&sCH[off]);
      fbl[n] = *reinterpret_cast<const short8*>(&sCL[off]);
    }
#pragma unroll
    for (int m = 0; m < 4; ++m) {
      const int off = swz16(wm * 64 + m * 16 + (lane & 15), kg);
      const short8 fah = *reinterpret_cast<const short8*>(&sXH[off]);
      const short8 fal = *reinterpret_cast<const short8*>(&sXL[off]);
#pragma unroll
      for (int n = 0; n < 4; ++n) {
        acc[m][n] = __builtin_amdgcn_mfma_f32_16x16x32_bf16(fah, fbh[n], acc[m][n], 0, 0, 0);
        acc[m][n] = __builtin_amdgcn_mfma_f32_16x16x32_bf16(fah, fbl[n], acc[m][n], 0, 0, 0);
        acc[m][n] = __builtin_amdgcn_mfma_f32_16x16x32_bf16(fal, fbh[n], acc[m][n], 0, 0, 0);
      }
    }
  }

  const int lr = lane >> 4, lc = lane & 15;
  const int tile = blockIdx.y * 2 + wn;
#pragma unroll
  for (int m = 0; m < 4; ++m) {
    float xnv[4];
#pragma unroll
    for (int j = 0; j < 4; ++j) xnv[j] = xn[row0 + wm * 64 + m * 16 + lr * 4 + j];
    float pm[4] = {INFINITY, INFINITY, INFINITY, INFINITY};
#pragma unroll
    for (int n = 0; n < 4; ++n) {
      const float cnv = cn[kc0 + wn * 64 + n * 16 + lc];
#pragma unroll
      for (int j = 0; j < 4; ++j) {
        const float A = xnv[j] + cnv;
        const float p = fmaf(-2.f, acc[m][n][j], A - xnv[j]);
        pm[j] = fminf(pm[j], p);
      }
    }
#pragma unroll
    for (int off = 1; off < 16; off <<= 1) {
#pragma unroll
      for (int j = 0; j < 4; ++j) pm[j] = fminf(pm[j], __shfl_xor(pm[j], off));
    }
    if (lc == 0) {
#pragma unroll
      for (int j = 0; j < 4; ++j) {
        const int row = row0 + wm * 64 + m * 16 + lr * 4 + j;
        atomicMin(&tmin[(size_t)row * 64 + tile], mono(pm[j]));
      }
    }
  }
}

__global__ __launch_bounds__(256) void vq_rescore(const float* __restrict__ x,
                                                  const float* __restrict__ cb,
                                                  const float* __restrict__ xn,
                                                  const float* __restrict__ cn,
                                                  const unsigned* __restrict__ tmin,
                                                  int* __restrict__ inds) {
  const int lane = threadIdx.x & 63;
  const int row = blockIdx.x * 4 + (threadIdx.x >> 6);
  const unsigned tv = tmin[(size_t)row * 64 + lane];
  unsigned mv = tv;
#pragma unroll
  for (int off = 32; off; off >>= 1) mv = min(mv, (unsigned)__shfl_xor((int)mv, off));
  const float xnr = xn[row];
  const float thresh = unmono(mv) + (xnr * 3e-7f + 4e-6f);
  const unsigned tq = mono(thresh);
  unsigned long long qmask = __ballot(tv <= tq);

  const float* xp = x + (size_t)row * DD;
  unsigned long long best = ~0ull;
  while (qmask) {
    const int s = __ffsll(qmask) - 1;
    qmask &= qmask - 1;
    const int k = s * 64 + lane;
    const float* cp = cb + (size_t)k * DD;
    float dot = 0.f;
#pragma unroll 8
    for (int d = 0; d < DD; ++d) dot = fmaf(xp[d], cp[d], dot);
    const float A = xnr + cn[k];
    const float dist = fmaf(-2.f, dot, A);
    const unsigned long long cand = ((unsigned long long)mono(dist) << 32) | (unsigned)k;
    best = best < cand ? best : cand;
  }
#pragma unroll
  for (int off = 32; off; off >>= 1) {
    const unsigned long long o = __shfl_xor(best, off);
    best = best < o ? best : o;
  }
  if (lane == 0) inds[row] = (int)(best & 0xffffffffu);
}

// ============ gather + STE output ============
__global__ __launch_bounds__(256) void vq_out(const float* __restrict__ x,
                                              const float* __restrict__ cb,
                                              const int* __restrict__ inds,
                                              float* __restrict__ out) {
  const int w = (blockIdx.x * blockDim.x + threadIdx.x) >> 6;
  const int lane = threadIdx.x & 63;
  if (w >= NN) return;
  const int k = inds[w];
  const float4 xv = *reinterpret_cast<const float4*>(x + (size_t)w * DD + lane * 4);
  const float4 cv = *reinterpret_cast<const float4*>(cb + (size_t)k * DD + lane * 4);
  float4 o;
  o.x = xv.x + (cv.x - xv.x);
  o.y = xv.y + (cv.y - xv.y);
  o.z = xv.z + (cv.z - xv.z);
  o.w = xv.w + (cv.w - xv.w);
  *reinterpret_cast<float4*>(out + (size_t)w * DD + lane * 4) = o;
}

extern "C" void kernel_launch(void* const* d_in, const int* in_sizes, int n_in,
                              void* d_out, int out_size, void* d_ws, size_t ws_size,
                              hipStream_t stream) {
  const float* x = (const float*)d_in[0];
  const float* cb = (const float*)d_in[1];
  float* out = (float*)d_out;
  char* ws = (char*)d_ws;

  float* xn = (float*)ws;
  float* cn = (float*)(ws + 131072);
  constexpr size_t BASE = 147456;

  // fast-path layout: xh 16MB | ch 2MB | tmin16 32MB | inds 128KB
  constexpr size_t XH_OFF = BASE;
  constexpr size_t CH_OFF = XH_OFF + (size_t)NN * DD * 2;
  constexpr size_t T16_OFF = CH_OFF + (size_t)KK * DD * 2;
  constexpr size_t INDS_OFF = T16_OFF + (size_t)NN * 256 * 4;
  constexpr size_t NEED_FAST = INDS_OFF + (size_t)NN * 4;  // ~50.6MB

  if (ws_size >= NEED_FAST) {
    unsigned short* xh = (unsigned short*)(ws + XH_OFF);
    unsigned short* ch = (unsigned short*)(ws + CH_OFF);
    unsigned* tmin16 = (unsigned*)(ws + T16_OFF);
    int* inds = (int*)(ws + INDS_OFF);

    vq_norms<<<NN / 256, 256, 0, stream>>>(x, xn, NN);
    vq_norms<<<KK / 256, 256, 0, stream>>>(cb, cn, KK);
    vq_split_hi<<<(NN * DD / 8) / 256, 256, 0, stream>>>(x, xh);
    vq_split_hi<<<(KK * DD / 8) / 256, 256, 0, stream>>>(cb, ch);
    dim3 mgrid(KK / 128, NN / 128);  // x = col-blocks, y = row-blocks
    vq_mfma2<<<mgrid, 256, 0, stream>>>(xh, ch, xn, cn, tmin16);
    vq_rescore16<<<NN / 4, 256, 0, stream>>>(x, cb, xn, cn, tmin16, inds);
    vq_out<<<NN / 4, 256, 0, stream>>>(x, cb, inds, out);
  } else {
    // round-7 fallback (proven)
    unsigned* tmin = (unsigned*)(ws + BASE);
    int* inds = (int*)(ws + BASE + (size_t)NN * 64 * 4);

    vq_init<<<(NN * 64) / 256, 256, 0, stream>>>(tmin, NN * 64);
    vq_norms<<<NN / 256, 256, 0, stream>>>(x, xn, NN);
    vq_norms<<<KK / 256, 256, 0, stream>>>(cb, cn, KK);
    dim3 mgrid(NN / 128, KK / 128);
    vq_mfma<<<mgrid, 256, 0, stream>>>(x, cb, xn, cn, tmin);
    vq_rescore<<<NN / 4, 256, 0, stream>>>(x, cb, xn, cn, tmin, inds);
    vq_out<<<NN / 4, 256, 0, stream>>>(x, cb, inds, out);
  }
}